// Round 10
// baseline (206.925 us; speedup 1.0000x reference)
//
#include <hip/hip_runtime.h>
#include <hip/hip_bf16.h>

#define BB 4
#define TT 2048
#define CC 1024
#define HH 16
#define HD 64
#define NQ (3*CC)
// 1/sqrt(64) * log2(e): attention done in exp2 domain
#define QSCALE 0.18033688011112042f

typedef __attribute__((ext_vector_type(8))) short bf16x8;
typedef __attribute__((ext_vector_type(4))) short short4_t;
typedef __attribute__((ext_vector_type(4))) float f32x4;

#define MFMA(a,b,c) __builtin_amdgcn_mfma_f32_16x16x32_bf16(a,b,c,0,0,0)

// async global->LDS, 16B per lane; LDS dest is wave-uniform base + lane*16
#define ASYNC16(gsrc, ldst) \
  __builtin_amdgcn_global_load_lds((const __attribute__((address_space(1))) void*)(gsrc), \
                                   (__attribute__((address_space(3))) void*)(ldst), 16, 0, 0)

// row-swizzle for 64-short-stride LDS tiles (16B-chunk granularity)
#define SWZA(row) (((((row) & 7) + (((row) >> 3) & 3)) & 7) << 3)

static __device__ __forceinline__ short f2bf(float f){
    union { float f; unsigned u; } v; v.f = f;
    unsigned r = v.u + 0x7FFFu + ((v.u >> 16) & 1u);   // RNE
    return (short)(r >> 16);
}
// packed f32x2 -> bf16x2 (RNE), single HW instruction
static __device__ __forceinline__ unsigned cvtpk(float a, float b){
    unsigned r;
    asm("v_cvt_pk_bf16_f32 %0, %1, %2" : "=v"(r) : "v"(a), "v"(b));
    return r;
}

// ---------------- prepass: x fp32 -> bf16 (row-major, unchanged layout)
__global__ __launch_bounds__(256)
void convert_x(const float* __restrict__ x, short* __restrict__ xb)
{
    int i = (blockIdx.x * 256 + threadIdx.x) * 8;
    float4 a = *reinterpret_cast<const float4*>(&x[i]);
    float4 b = *reinterpret_cast<const float4*>(&x[i+4]);
    bf16x8 o = { f2bf(a.x), f2bf(a.y), f2bf(a.z), f2bf(a.w),
                 f2bf(b.x), f2bf(b.y), f2bf(b.z), f2bf(b.w) };
    *reinterpret_cast<bf16x8*>(&xb[i]) = o;
}

// ---------------- prepass: w fp32 [K=1024][N] -> wT bf16 [N][1024]
__global__ __launch_bounds__(256)
void transpose_w(const float* __restrict__ w, short* __restrict__ wT, int N)
{
    __shared__ short sm[64*72];
    const int kt0 = blockIdx.x * 64;
    const int nt0 = blockIdx.y * 64;
    const int t = threadIdx.x;
    const int r  = t >> 4;
    const int c4 = (t & 15) * 4;
#pragma unroll
    for (int it = 0; it < 4; it++){
        int k = r + it*16;
        float4 v = *reinterpret_cast<const float4*>(&w[(size_t)(kt0 + k)*N + nt0 + c4]);
        sm[(c4+0)*72 + k] = f2bf(v.x);
        sm[(c4+1)*72 + k] = f2bf(v.y);
        sm[(c4+2)*72 + k] = f2bf(v.z);
        sm[(c4+3)*72 + k] = f2bf(v.w);
    }
    __syncthreads();
    const int nl = t >> 2;
    const int kc = (t & 3) * 16;
    bf16x8 o0 = *reinterpret_cast<const bf16x8*>(&sm[nl*72 + kc]);
    bf16x8 o1 = *reinterpret_cast<const bf16x8*>(&sm[nl*72 + kc + 8]);
    short* dst = &wT[(size_t)(nt0 + nl)*CC + kt0 + kc];
    *reinterpret_cast<bf16x8*>(dst)     = o0;
    *reinterpret_cast<bf16x8*>(dst + 8) = o1;
}

// ---------------- QKV GEMM (bf16): xb [8192,1024] @ wT^T -> q/k bf16 [B,H,T,HD],
// v written TRANSPOSED to vtb [B,H,HD,T] via LDS bounce (v-blocks: bn 16..23).
__global__ __launch_bounds__(256, 2)
void qkv_gemm(const short* __restrict__ xb, const short* __restrict__ wT,
              const float* __restrict__ bias,
              short* __restrict__ qb, short* __restrict__ kb, short* __restrict__ vtb)
{
    __shared__ short smem[128*136];      // As+Bs (16384) and epilogue Ts (17408)
    short* As = smem;                    // [128*64]
    short* Bs = smem + 8192;             // [128*64]
    const int bid = blockIdx.x;
    const int swz = (bid & 7) * 192 + (bid >> 3);   // 1536 blocks, bijective XCD swizzle
    const int bm = swz / (NQ/128);
    const int bn = swz % (NQ/128);
    const int m0 = bm*128, n0 = bn*128;
    const int t  = threadIdx.x;
    const int wid = t >> 6, lane = t & 63;
    const int wr = wid >> 1, wc = wid & 1;
    const int l15 = lane & 15, lh = lane >> 4;

    f32x4 acc[4][4];
#pragma unroll
    for (int i=0;i<4;i++)
#pragma unroll
      for (int j=0;j<4;j++) acc[i][j] = (f32x4)0.f;

    for (int k0 = 0; k0 < CC; k0 += 64) {
        __syncthreads();
#pragma unroll
        for (int i=0;i<4;i++){
            int u   = (wid*4 + i)*64 + lane;
            int row = u >> 3, c = u & 7;
            int cs  = c ^ (row & 7);      // inverse-swizzled source chunk
            ASYNC16(&xb[(size_t)(m0+row)*CC + k0 + cs*8], &As[(wid*4+i)*512]);
            ASYNC16(&wT[(size_t)(n0+row)*CC + k0 + cs*8], &Bs[(wid*4+i)*512]);
        }
        __syncthreads();
#pragma unroll
        for (int ks=0;ks<2;ks++){
            bf16x8 a[4], b[4];
#pragma unroll
            for (int m=0;m<4;m++){
                int row = wr*64 + m*16 + l15;
                a[m] = *reinterpret_cast<const bf16x8*>(&As[row*64 + (((ks<<2)|lh) ^ (row&7))*8]);
            }
#pragma unroll
            for (int n=0;n<4;n++){
                int col = wc*64 + n*16 + l15;
                b[n] = *reinterpret_cast<const bf16x8*>(&Bs[col*64 + (((ks<<2)|lh) ^ (col&7))*8]);
            }
#pragma unroll
            for (int m=0;m<4;m++)
#pragma unroll
              for (int n=0;n<4;n++)
                acc[m][n] = MFMA(a[m], b[n], acc[m][n]);
        }
    }

    if (n0 < 2*CC) {
        // q/k epilogue: scatter [B,H,T,HD]; fold exp2-domain scale into q
#pragma unroll
        for (int n=0;n<4;n++){
            int col = n0 + wc*64 + n*16 + l15;
            int sect = col >> 10;
            int cc = col & 1023;
            int h = cc >> 6, d = cc & 63;
            float bv = bias[col];
            short* dst = (sect==0) ? qb : kb;
            float mul = (sect==0) ? QSCALE : 1.f;
#pragma unroll
            for (int m=0;m<4;m++)
#pragma unroll
              for (int r=0;r<4;r++){
                int row = m0 + wr*64 + m*16 + lh*4 + r;
                int b_ = row >> 11, tt_ = row & (TT-1);
                float v = (acc[m][n][r] + bv) * mul;
                dst[((size_t)(b_*HH + h)*TT + tt_)*HD + d] = f2bf(v);
              }
        }
    } else {
        // v epilogue: transpose 128x128 tile via LDS -> vtb [bh][d][T] coalesced
        __syncthreads();                 // all waves done reading As/Bs
        short* Ts = smem;                // [128 cols][136]
#pragma unroll
        for (int n=0;n<4;n++){
            int colL = wc*64 + n*16 + l15;
            float bv = bias[n0 + colL];
#pragma unroll
            for (int m=0;m<4;m++){
                int rowL = wr*64 + m*16 + lh*4;
                short4_t pk = { f2bf(acc[m][n][0]+bv), f2bf(acc[m][n][1]+bv),
                                f2bf(acc[m][n][2]+bv), f2bf(acc[m][n][3]+bv) };
                *reinterpret_cast<short4_t*>(&Ts[colL*136 + rowL]) = pk;
            }
        }
        __syncthreads();
        const int b_ = m0 >> 11, t0 = m0 & (TT-1);
        const int cc0 = n0 - 2*CC;
#pragma unroll
        for (int pass=0;pass<2;pass++){
            int c = (t >> 2) + pass*64;
            int vcol = cc0 + c;
            short* dst = vtb + ((size_t)(b_*HH + (vcol>>6))*HD + (vcol&63))*TT + t0;
#pragma unroll
            for (int it=0;it<4;it++){
                int r0 = (t & 3)*8 + it*32;
                *reinterpret_cast<bf16x8*>(&dst[r0]) =
                    *reinterpret_cast<const bf16x8*>(&Ts[c*136 + r0]);
            }
        }
    }
}

// ---------------- Flash attention v10: unpaired 128-row q-tiles, swapped QK^T,
// K/V via global_load_lds, Ps shrunk to 16 rows (pa held in regs) -> 40KB LDS,
// 4 blocks/CU, contiguous den+PV MFMA cluster.
__global__ __launch_bounds__(256, 4)
void attn_kernel(const short* __restrict__ qb, const short* __restrict__ kb,
                 const short* __restrict__ vtb, short* __restrict__ yb)
{
    __shared__ short Ks[2][64*64];   // [kv][d] bf16, SWZA chunk swizzle
    __shared__ short Vt[2][64*64];   // [d][kv] bf16, SWZA chunk swizzle
    __shared__ short Ps[4][16*64];   // per-wave P [qloc16][kv] bf16, SWZA

    const int bh = blockIdx.x;            // 0..63 : id%8==bh%8 -> same-head blocks share XCD
    const int qt = 15 - blockIdx.y;       // descending: longest blocks dispatch first
    const int b_ = bh >> 4, h = bh & 15;
    const short* qp  = qb  + (size_t)bh*TT*HD;
    const short* kp  = kb  + (size_t)bh*TT*HD;
    const short* vtp = vtb + (size_t)bh*HD*TT;   // [d][T]
    const int t = threadIdx.x, wid = t >> 6, lane = t & 63;
    const int l15 = lane & 15, lh = lane >> 4;

    // hoisted LDS byte offsets; row = i*16+l15 reads at (row*64 + ks*32 + lh*8) ^ SWZA(row)
    int kvoffB[8];   // [ks*4+i]
#pragma unroll
    for (int ks=0;ks<2;ks++)
#pragma unroll
      for (int i=0;i<4;i++){
        int row = i*16 + l15;
        kvoffB[ks*4+i] = ((row*64 + ks*32 + lh*8) ^ SWZA(row)) * 2;
      }
    int pwB[4];      // P-write offsets (uint2), row = l15
#pragma unroll
    for (int f=0;f<4;f++)
        pwB[f] = ((l15*64 + f*16 + lh*4) ^ SWZA(l15)) * 2;
    char* KsB = (char*)&Ks[0][0];
    char* VtB = (char*)&Vt[0][0];
    char* PsB = (char*)&Ps[wid][0];

    // staging map: u = (wid*2+i)*64 + lane; row = u>>3, chunk = u&7 (16B chunks)
    const int su0 = (wid*2+0)*64 + lane;
    const int su1 = (wid*2+1)*64 + lane;
    const int sr0 = su0 >> 3, sc0 = (su0 & 7) ^ (SWZA(su0 >> 3) >> 3);
    const int sr1 = su1 >> 3, sc1 = (su1 & 7) ^ (SWZA(su1 >> 3) >> 3);

    // running global pointers (advance after each staged tile)
    const short* kg0 = kp  + (size_t)sr0*HD + sc0*8;
    const short* kg1 = kp  + (size_t)sr1*HD + sc1*8;
    const short* vg0 = vtp + (size_t)sr0*TT + sc0*8;
    const short* vg1 = vtp + (size_t)sr1*TT + sc1*8;

    const bf16x8 ones = { 0x3F80,0x3F80,0x3F80,0x3F80,0x3F80,0x3F80,0x3F80,0x3F80 };

    auto stageN = [&](int buf){
        ASYNC16(kg0, &Ks[buf][(wid*2+0)*512]);
        ASYNC16(kg1, &Ks[buf][(wid*2+1)*512]);
        ASYNC16(vg0, &Vt[buf][(wid*2+0)*512]);
        ASYNC16(vg1, &Vt[buf][(wid*2+1)*512]);
        kg0 += 64*HD; kg1 += 64*HD; vg0 += 64; vg1 += 64;
    };

    const int wq0 = qt*128 + wid*32;      // this wave's first q row

    bf16x8 qf[2][2];
#pragma unroll
    for (int m=0;m<2;m++)
#pragma unroll
      for (int ks=0;ks<2;ks++)
        qf[m][ks] = *reinterpret_cast<const bf16x8*>(
            &qp[(size_t)(wq0 + m*16 + l15)*HD + ks*32 + lh*8]);

    f32x4 po[2][4];
    f32x4 pden[2];
#pragma unroll
    for (int m=0;m<2;m++){
        pden[m] = (f32x4)0.f;
#pragma unroll
        for (int n=0;n<4;n++) po[m][n] = (f32x4)0.f;
    }

    const int ntk = 2*(qt + 1);           // always even

    stageN(0);
    __syncthreads();   // implicit vmcnt(0) drain before barrier

    for (int kt = 0; kt < ntk; ){
#pragma unroll
        for (int cur = 0; cur < 2; cur++, kt++){    // cur is compile-time after unroll
            const int kv0 = kt*64;
            if (kt+1 < ntk) stageN(cur ^ 1);        // fly during compute

            if (kv0 <= wq0 + 31){     // wave-uniform causal activity test
                // S^T = K Q^T : per lane q = l15 (const), kv = f*16 + lh*4 + r
                f32x4 s[2][4];
#pragma unroll
                for (int m=0;m<2;m++)
#pragma unroll
                  for (int f=0;f<4;f++) s[m][f] = (f32x4)0.f;
                __builtin_amdgcn_s_setprio(1);
#pragma unroll
                for (int ks=0;ks<2;ks++){
#pragma unroll
                    for (int f=0;f<4;f++){
                        bf16x8 kf = *reinterpret_cast<const bf16x8*>(
                            KsB + cur*8192 + kvoffB[ks*4+f]);
                        s[0][f] = MFMA(kf, qf[0][ks], s[0][f]);
                        s[1][f] = MFMA(kf, qf[1][ks], s[1][f]);
                    }
                }
                __builtin_amdgcn_s_setprio(0);
                // causal mask (straddling tiles only): q is per-lane scalar
#pragma unroll
                for (int m=0;m<2;m++){
                    if (kv0 + 63 > wq0 + m*16){
                        int qm = wq0 + m*16 + l15;
#pragma unroll
                        for (int f=0;f<4;f++)
#pragma unroll
                          for (int r=0;r<4;r++){
                            int kv = kv0 + f*16 + lh*4 + r;
                            if (kv > qm) s[m][f][r] = -1e30f;
                          }
                    }
                }
                // P = exp2(S'); per-m: pack -> Ps(16 rows) -> pa regs (Ps reused for m=1;
                // in-order per-wave LDS + may-alias ordering keeps RAW/WAR safe)
                bf16x8 pa[2][2];
#pragma unroll
                for (int m=0;m<2;m++){
#pragma unroll
                    for (int f=0;f<4;f++){
                        uint2 pk;
                        pk.x = cvtpk(exp2f(s[m][f][0]), exp2f(s[m][f][1]));
                        pk.y = cvtpk(exp2f(s[m][f][2]), exp2f(s[m][f][3]));
                        *reinterpret_cast<uint2*>(PsB + pwB[f]) = pk;
                    }
                    pa[m][0] = *reinterpret_cast<const bf16x8*>(PsB + kvoffB[0]);
                    pa[m][1] = *reinterpret_cast<const bf16x8*>(PsB + kvoffB[4]);
                }
                // O += P V ; den += P * 1   (contiguous 20-MFMA cluster)
                __builtin_amdgcn_s_setprio(1);
#pragma unroll
                for (int k2=0;k2<2;k2++){
                    pden[0] = MFMA(pa[0][k2], ones, pden[0]);
                    pden[1] = MFMA(pa[1][k2], ones, pden[1]);
#pragma unroll
                    for (int n=0;n<4;n++){
                        bf16x8 vf = *reinterpret_cast<const bf16x8*>(
                            VtB + cur*8192 + kvoffB[k2*4+n]);
                        po[0][n] = MFMA(pa[0][k2], vf, po[0][n]);
                        po[1][n] = MFMA(pa[1][k2], vf, po[1][n]);
                    }
                }
                __builtin_amdgcn_s_setprio(0);
            }

            __syncthreads();   // drains staged loads (vmcnt) + publishes next buffer
        }
    }

    // epilogue -> y [B,T,C] bf16
#pragma unroll
    for (int m=0;m<2;m++){
        float rcp[4];
#pragma unroll
        for (int r=0;r<4;r++) rcp[r] = 1.f / pden[m][r];
#pragma unroll
        for (int n=0;n<4;n++)
#pragma unroll
          for (int r=0;r<4;r++){
            int q = wq0 + m*16 + lh*4 + r;
            int dd = n*16 + l15;
            yb[(size_t)(b_*TT + q)*CC + h*HD + dd] = f2bf(po[m][n][r] * rcp[r]);
          }
    }
}

// ---------------- Output projection (bf16): y [8192,1024] @ wpT^T + bias -> fp32 out
__global__ __launch_bounds__(256, 2)
void proj_gemm(const short* __restrict__ y, const short* __restrict__ wpT,
               const float* __restrict__ bias, float* __restrict__ out)
{
    __shared__ short As[128*64];
    __shared__ short Bs[128*64];
    const int bid = blockIdx.x;
    const int swz = (bid & 7) * 64 + (bid >> 3);   // 512 blocks
    const int bm = swz >> 3, bn = swz & 7;
    const int m0 = bm*128, n0 = bn*128;
    const int t  = threadIdx.x;
    const int wid = t >> 6, lane = t & 63;
    const int wr = wid >> 1, wc = wid & 1;
    const int l15 = lane & 15, lh = lane >> 4;

    f32x4 acc[4][4];
#pragma unroll
    for (int i=0;i<4;i++)
#pragma unroll
      for (int j=0;j<4;j++) acc[i][j] = (f32x4)0.f;

    for (int k0 = 0; k0 < CC; k0 += 64) {
        __syncthreads();
#pragma unroll
        for (int i=0;i<4;i++){
            int u   = (wid*4 + i)*64 + lane;
            int row = u >> 3, c = u & 7;
            int cs  = c ^ (row & 7);
            ASYNC16(&y[(size_t)(m0+row)*CC + k0 + cs*8],   &As[(wid*4+i)*512]);
            ASYNC16(&wpT[(size_t)(n0+row)*CC + k0 + cs*8], &Bs[(wid*4+i)*512]);
        }
        __syncthreads();
#pragma unroll
        for (int ks=0;ks<2;ks++){
            bf16x8 a[4], b[4];
#pragma unroll
            for (int m=0;m<4;m++){
                int row = wr*64 + m*16 + l15;
                a[m] = *reinterpret_cast<const bf16x8*>(&As[row*64 + (((ks<<2)|lh) ^ (row&7))*8]);
            }
#pragma unroll
            for (int n=0;n<4;n++){
                int col = wc*64 + n*16 + l15;
                b[n] = *reinterpret_cast<const bf16x8*>(&Bs[col*64 + (((ks<<2)|lh) ^ (col&7))*8]);
            }
#pragma unroll
            for (int m=0;m<4;m++)
#pragma unroll
              for (int n=0;n<4;n++)
                acc[m][n] = MFMA(a[m], b[n], acc[m][n]);
        }
    }

#pragma unroll
    for (int n=0;n<4;n++){
        int col = n0 + wc*64 + n*16 + l15;
        float bv = bias[col];
#pragma unroll
        for (int m=0;m<4;m++)
#pragma unroll
          for (int r=0;r<4;r++){
            int row = m0 + wr*64 + m*16 + lh*4 + r;
            out[(size_t)row*CC + col] = acc[m][n][r] + bv;
          }
    }
}

extern "C" void kernel_launch(void* const* d_in, const int* in_sizes, int n_in,
                              void* d_out, int out_size, void* d_ws, size_t ws_size,
                              hipStream_t stream) {
    const float* x      = (const float*)d_in[0];
    const float* w_attn = (const float*)d_in[1];
    const float* b_attn = (const float*)d_in[2];
    const float* w_proj = (const float*)d_in[3];
    const float* b_proj = (const float*)d_in[4];
    float* out = (float*)d_out;

    const size_t S = (size_t)BB*TT*CC;   // 8.4M elems
    short* qb  = (short*)d_ws;           // bf16 [B,H,T,HD]
    short* kb  = qb + S;
    short* vtb = kb + S;                 // bf16 [B,H,HD,T]  (V written transposed by qkv)
    short* yx  = vtb + S;                // x-bf16 during prepass+qkv; y-bf16 after attn
    short* wT  = yx + S;                 // bf16 [3072][1024]
    short* wpT = wT + (size_t)NQ*CC;     // bf16 [1024][1024]

    convert_x<<<dim3(S/(256*8)), 256, 0, stream>>>(x, yx);
    transpose_w<<<dim3(CC/64, NQ/64), 256, 0, stream>>>(w_attn, wT, NQ);
    transpose_w<<<dim3(CC/64, CC/64), 256, 0, stream>>>(w_proj, wpT, CC);
    qkv_gemm<<<dim3((BB*TT/128)*(NQ/128)), 256, 0, stream>>>(yx, wT, b_attn, qb, kb, vtb);
    attn_kernel<<<dim3(BB*HH, TT/128), 256, 0, stream>>>(qb, kb, vtb, yx);
    proj_gemm<<<dim3((BB*TT/128)*(CC/128)), 256, 0, stream>>>(yx, wpT, b_proj, out);
}

// Round 11
// 171.001 us; speedup vs baseline: 1.2101x; 1.2101x over previous
//
#include <hip/hip_runtime.h>
#include <hip/hip_bf16.h>

#define BB 4
#define TT 2048
#define CC 1024
#define HH 16
#define HD 64
#define NQ (3*CC)
// 1/sqrt(64) * log2(e): attention done in exp2 domain
#define QSCALE 0.18033688011112042f

typedef __attribute__((ext_vector_type(8))) short bf16x8;
typedef __attribute__((ext_vector_type(4))) short short4_t;
typedef __attribute__((ext_vector_type(4))) float f32x4;

#define MFMA(a,b,c) __builtin_amdgcn_mfma_f32_16x16x32_bf16(a,b,c,0,0,0)

// async global->LDS, 16B per lane; LDS dest is wave-uniform base + lane*16
#define ASYNC16(gsrc, ldst) \
  __builtin_amdgcn_global_load_lds((const __attribute__((address_space(1))) void*)(gsrc), \
                                   (__attribute__((address_space(3))) void*)(ldst), 16, 0, 0)

// row-swizzle for 64-short-stride LDS tiles (16B-chunk granularity)
#define SWZA(row) (((((row) & 7) + (((row) >> 3) & 3)) & 7) << 3)

static __device__ __forceinline__ short f2bf(float f){
    union { float f; unsigned u; } v; v.f = f;
    unsigned r = v.u + 0x7FFFu + ((v.u >> 16) & 1u);   // RNE
    return (short)(r >> 16);
}
// packed f32x2 -> bf16x2 (RNE), single HW instruction
static __device__ __forceinline__ unsigned cvtpk(float a, float b){
    unsigned r;
    asm("v_cvt_pk_bf16_f32 %0, %1, %2" : "=v"(r) : "v"(a), "v"(b));
    return r;
}

// ---------------- prepass: x fp32 -> bf16 (row-major, unchanged layout)
__global__ __launch_bounds__(256)
void convert_x(const float* __restrict__ x, short* __restrict__ xb)
{
    int i = (blockIdx.x * 256 + threadIdx.x) * 8;
    float4 a = *reinterpret_cast<const float4*>(&x[i]);
    float4 b = *reinterpret_cast<const float4*>(&x[i+4]);
    bf16x8 o = { f2bf(a.x), f2bf(a.y), f2bf(a.z), f2bf(a.w),
                 f2bf(b.x), f2bf(b.y), f2bf(b.z), f2bf(b.w) };
    *reinterpret_cast<bf16x8*>(&xb[i]) = o;
}

// ---------------- prepass: w fp32 [K=1024][N] -> wT bf16 [N][1024]
__global__ __launch_bounds__(256)
void transpose_w(const float* __restrict__ w, short* __restrict__ wT, int N)
{
    __shared__ short sm[64*72];
    const int kt0 = blockIdx.x * 64;
    const int nt0 = blockIdx.y * 64;
    const int t = threadIdx.x;
    const int r  = t >> 4;
    const int c4 = (t & 15) * 4;
#pragma unroll
    for (int it = 0; it < 4; it++){
        int k = r + it*16;
        float4 v = *reinterpret_cast<const float4*>(&w[(size_t)(kt0 + k)*N + nt0 + c4]);
        sm[(c4+0)*72 + k] = f2bf(v.x);
        sm[(c4+1)*72 + k] = f2bf(v.y);
        sm[(c4+2)*72 + k] = f2bf(v.z);
        sm[(c4+3)*72 + k] = f2bf(v.w);
    }
    __syncthreads();
    const int nl = t >> 2;
    const int kc = (t & 3) * 16;
    bf16x8 o0 = *reinterpret_cast<const bf16x8*>(&sm[nl*72 + kc]);
    bf16x8 o1 = *reinterpret_cast<const bf16x8*>(&sm[nl*72 + kc + 8]);
    short* dst = &wT[(size_t)(nt0 + nl)*CC + kt0 + kc];
    *reinterpret_cast<bf16x8*>(dst)     = o0;
    *reinterpret_cast<bf16x8*>(dst + 8) = o1;
}

// ---------------- QKV GEMM (bf16): xb [8192,1024] @ wT^T -> q/k bf16 [B,H,T,HD],
// v written TRANSPOSED to vtb [B,H,HD,T] via LDS bounce (v-blocks: bn 16..23).
__global__ __launch_bounds__(256, 2)
void qkv_gemm(const short* __restrict__ xb, const short* __restrict__ wT,
              const float* __restrict__ bias,
              short* __restrict__ qb, short* __restrict__ kb, short* __restrict__ vtb)
{
    __shared__ short smem[128*136];      // As+Bs (16384) and epilogue Ts (17408)
    short* As = smem;                    // [128*64]
    short* Bs = smem + 8192;             // [128*64]
    const int bid = blockIdx.x;
    const int swz = (bid & 7) * 192 + (bid >> 3);   // 1536 blocks, bijective XCD swizzle
    const int bm = swz / (NQ/128);
    const int bn = swz % (NQ/128);
    const int m0 = bm*128, n0 = bn*128;
    const int t  = threadIdx.x;
    const int wid = t >> 6, lane = t & 63;
    const int wr = wid >> 1, wc = wid & 1;
    const int l15 = lane & 15, lh = lane >> 4;

    f32x4 acc[4][4];
#pragma unroll
    for (int i=0;i<4;i++)
#pragma unroll
      for (int j=0;j<4;j++) acc[i][j] = (f32x4)0.f;

    for (int k0 = 0; k0 < CC; k0 += 64) {
        __syncthreads();
#pragma unroll
        for (int i=0;i<4;i++){
            int u   = (wid*4 + i)*64 + lane;
            int row = u >> 3, c = u & 7;
            int cs  = c ^ (row & 7);      // inverse-swizzled source chunk
            ASYNC16(&xb[(size_t)(m0+row)*CC + k0 + cs*8], &As[(wid*4+i)*512]);
            ASYNC16(&wT[(size_t)(n0+row)*CC + k0 + cs*8], &Bs[(wid*4+i)*512]);
        }
        __syncthreads();
#pragma unroll
        for (int ks=0;ks<2;ks++){
            bf16x8 a[4], b[4];
#pragma unroll
            for (int m=0;m<4;m++){
                int row = wr*64 + m*16 + l15;
                a[m] = *reinterpret_cast<const bf16x8*>(&As[row*64 + (((ks<<2)|lh) ^ (row&7))*8]);
            }
#pragma unroll
            for (int n=0;n<4;n++){
                int col = wc*64 + n*16 + l15;
                b[n] = *reinterpret_cast<const bf16x8*>(&Bs[col*64 + (((ks<<2)|lh) ^ (col&7))*8]);
            }
#pragma unroll
            for (int m=0;m<4;m++)
#pragma unroll
              for (int n=0;n<4;n++)
                acc[m][n] = MFMA(a[m], b[n], acc[m][n]);
        }
    }

    if (n0 < 2*CC) {
        // q/k epilogue: scatter [B,H,T,HD]; fold exp2-domain scale into q
#pragma unroll
        for (int n=0;n<4;n++){
            int col = n0 + wc*64 + n*16 + l15;
            int sect = col >> 10;
            int cc = col & 1023;
            int h = cc >> 6, d = cc & 63;
            float bv = bias[col];
            short* dst = (sect==0) ? qb : kb;
            float mul = (sect==0) ? QSCALE : 1.f;
#pragma unroll
            for (int m=0;m<4;m++)
#pragma unroll
              for (int r=0;r<4;r++){
                int row = m0 + wr*64 + m*16 + lh*4 + r;
                int b_ = row >> 11, tt_ = row & (TT-1);
                float v = (acc[m][n][r] + bv) * mul;
                dst[((size_t)(b_*HH + h)*TT + tt_)*HD + d] = f2bf(v);
              }
        }
    } else {
        // v epilogue: transpose 128x128 tile via LDS -> vtb [bh][d][T] coalesced
        __syncthreads();                 // all waves done reading As/Bs
        short* Ts = smem;                // [128 cols][136]
#pragma unroll
        for (int n=0;n<4;n++){
            int colL = wc*64 + n*16 + l15;
            float bv = bias[n0 + colL];
#pragma unroll
            for (int m=0;m<4;m++){
                int rowL = wr*64 + m*16 + lh*4;
                short4_t pk = { f2bf(acc[m][n][0]+bv), f2bf(acc[m][n][1]+bv),
                                f2bf(acc[m][n][2]+bv), f2bf(acc[m][n][3]+bv) };
                *reinterpret_cast<short4_t*>(&Ts[colL*136 + rowL]) = pk;
            }
        }
        __syncthreads();
        const int b_ = m0 >> 11, t0 = m0 & (TT-1);
        const int cc0 = n0 - 2*CC;
#pragma unroll
        for (int pass=0;pass<2;pass++){
            int c = (t >> 2) + pass*64;
            int vcol = cc0 + c;
            short* dst = vtb + ((size_t)(b_*HH + (vcol>>6))*HD + (vcol&63))*TT + t0;
#pragma unroll
            for (int it=0;it<4;it++){
                int r0 = (t & 3)*8 + it*32;
                *reinterpret_cast<bf16x8*>(&dst[r0]) =
                    *reinterpret_cast<const bf16x8*>(&Ts[c*136 + r0]);
            }
        }
    }
}

// ---------------- Flash attention v9 (reverted R9 config): unpaired 128-row q-tiles,
// swapped QK^T, K/V via global_load_lds, hoisted LDS offsets, 3 blocks/CU.
__global__ __launch_bounds__(256, 3)
void attn_kernel(const short* __restrict__ qb, const short* __restrict__ kb,
                 const short* __restrict__ vtb, short* __restrict__ yb)
{
    __shared__ short Ks[2][64*64];   // [kv][d] bf16, SWZA chunk swizzle
    __shared__ short Vt[2][64*64];   // [d][kv] bf16, SWZA chunk swizzle
    __shared__ short Ps[4][32*64];   // per-wave P [qloc][kv] bf16, SWZA

    const int bh = blockIdx.x;            // 0..63 : id%8==bh%8 -> same-head blocks share XCD
    const int qt = 15 - blockIdx.y;       // descending: longest blocks dispatch first
    const int b_ = bh >> 4, h = bh & 15;
    const short* qp  = qb  + (size_t)bh*TT*HD;
    const short* kp  = kb  + (size_t)bh*TT*HD;
    const short* vtp = vtb + (size_t)bh*HD*TT;   // [d][T]
    const int t = threadIdx.x, wid = t >> 6, lane = t & 63;
    const int l15 = lane & 15, lh = lane >> 4;

    // ---- hoisted LDS byte offsets (static-indexed arrays -> register-resident)
    int kvoffB[8];   // [ks*4+i] : K-frag / V-frag / P-read offsets
#pragma unroll
    for (int ks=0;ks<2;ks++)
#pragma unroll
      for (int i=0;i<4;i++){
        int row = i*16 + l15;
        kvoffB[ks*4+i] = ((row*64 + ks*32 + lh*8) ^ SWZA(row)) * 2;
      }
    int pwB[8];      // [m*4+f] : P-write offsets (uint2)
#pragma unroll
    for (int m=0;m<2;m++){
        int qloc = m*16 + l15;
#pragma unroll
        for (int f=0;f<4;f++)
            pwB[m*4+f] = ((qloc*64 + f*16 + lh*4) ^ SWZA(qloc)) * 2;
    }
    char* KsB = (char*)&Ks[0][0];
    char* VtB = (char*)&Vt[0][0];
    char* PsB = (char*)&Ps[wid][0];

    // staging map: u = (wid*2+i)*64 + lane; row = u>>3, chunk = u&7 (16B chunks)
    const int su0 = (wid*2+0)*64 + lane;
    const int su1 = (wid*2+1)*64 + lane;
    const int sr0 = su0 >> 3, sc0 = (su0 & 7) ^ (SWZA(su0 >> 3) >> 3);
    const int sr1 = su1 >> 3, sc1 = (su1 & 7) ^ (SWZA(su1 >> 3) >> 3);

    // running global pointers (advance after each staged tile)
    const short* kg0 = kp  + (size_t)sr0*HD + sc0*8;
    const short* kg1 = kp  + (size_t)sr1*HD + sc1*8;
    const short* vg0 = vtp + (size_t)sr0*TT + sc0*8;
    const short* vg1 = vtp + (size_t)sr1*TT + sc1*8;

    const bf16x8 ones = { 0x3F80,0x3F80,0x3F80,0x3F80,0x3F80,0x3F80,0x3F80,0x3F80 };

    auto stageN = [&](int buf){
        ASYNC16(kg0, &Ks[buf][(wid*2+0)*512]);
        ASYNC16(kg1, &Ks[buf][(wid*2+1)*512]);
        ASYNC16(vg0, &Vt[buf][(wid*2+0)*512]);
        ASYNC16(vg1, &Vt[buf][(wid*2+1)*512]);
        kg0 += 64*HD; kg1 += 64*HD; vg0 += 64; vg1 += 64;
    };

    const int wq0 = qt*128 + wid*32;      // this wave's first q row

    bf16x8 qf[2][2];
#pragma unroll
    for (int m=0;m<2;m++)
#pragma unroll
      for (int ks=0;ks<2;ks++)
        qf[m][ks] = *reinterpret_cast<const bf16x8*>(
            &qp[(size_t)(wq0 + m*16 + l15)*HD + ks*32 + lh*8]);

    f32x4 po[2][4];
    f32x4 pden[2];
#pragma unroll
    for (int m=0;m<2;m++){
        pden[m] = (f32x4)0.f;
#pragma unroll
        for (int n=0;n<4;n++) po[m][n] = (f32x4)0.f;
    }

    const int ntk = 2*(qt + 1);           // always even

    stageN(0);
    __syncthreads();   // implicit vmcnt(0) drain before barrier

    for (int kt = 0; kt < ntk; ){
#pragma unroll
        for (int cur = 0; cur < 2; cur++, kt++){    // cur is compile-time after unroll
            const int kv0 = kt*64;
            if (kt+1 < ntk) stageN(cur ^ 1);        // fly during compute

            if (kv0 <= wq0 + 31){     // wave-uniform causal activity test
                // S^T = K Q^T : per lane q = l15 (const), kv = f*16 + lh*4 + r
                f32x4 s[2][4];
#pragma unroll
                for (int m=0;m<2;m++)
#pragma unroll
                  for (int f=0;f<4;f++) s[m][f] = (f32x4)0.f;
                __builtin_amdgcn_s_setprio(1);
#pragma unroll
                for (int ks=0;ks<2;ks++){
#pragma unroll
                    for (int f=0;f<4;f++){
                        bf16x8 kf = *reinterpret_cast<const bf16x8*>(
                            KsB + cur*8192 + kvoffB[ks*4+f]);
                        s[0][f] = MFMA(kf, qf[0][ks], s[0][f]);
                        s[1][f] = MFMA(kf, qf[1][ks], s[1][f]);
                    }
                }
                __builtin_amdgcn_s_setprio(0);
                // causal mask (straddling tiles only): q is per-lane scalar
#pragma unroll
                for (int m=0;m<2;m++){
                    if (kv0 + 63 > wq0 + m*16){
                        int qm = wq0 + m*16 + l15;
#pragma unroll
                        for (int f=0;f<4;f++)
#pragma unroll
                          for (int r=0;r<4;r++){
                            int kv = kv0 + f*16 + lh*4 + r;
                            if (kv > qm) s[m][f][r] = -1e30f;
                          }
                    }
                }
                // P = exp2(S'); pack via v_cvt_pk_bf16_f32; one b64 LDS write per f
#pragma unroll
                for (int m=0;m<2;m++){
#pragma unroll
                    for (int f=0;f<4;f++){
                        uint2 pk;
                        pk.x = cvtpk(exp2f(s[m][f][0]), exp2f(s[m][f][1]));
                        pk.y = cvtpk(exp2f(s[m][f][2]), exp2f(s[m][f][3]));
                        *reinterpret_cast<uint2*>(PsB + pwB[m*4+f]) = pk;
                    }
                }
                // O += P V ; den += P * 1  (ones-column via constant B-fragment)
                __builtin_amdgcn_s_setprio(1);
#pragma unroll
                for (int k2=0;k2<2;k2++){
                    bf16x8 pa[2];
#pragma unroll
                    for (int m=0;m<2;m++)
                        pa[m] = *reinterpret_cast<const bf16x8*>(PsB + kvoffB[k2*4+m]);
                    pden[0] = MFMA(pa[0], ones, pden[0]);
                    pden[1] = MFMA(pa[1], ones, pden[1]);
#pragma unroll
                    for (int n=0;n<4;n++){
                        bf16x8 vf = *reinterpret_cast<const bf16x8*>(
                            VtB + cur*8192 + kvoffB[k2*4+n]);
                        po[0][n] = MFMA(pa[0], vf, po[0][n]);
                        po[1][n] = MFMA(pa[1], vf, po[1][n]);
                    }
                }
                __builtin_amdgcn_s_setprio(0);
            }

            __syncthreads();   // drains staged loads (vmcnt) + publishes next buffer
        }
    }

    // epilogue -> y [B,T,C] bf16
#pragma unroll
    for (int m=0;m<2;m++){
        float rcp[4];
#pragma unroll
        for (int r=0;r<4;r++) rcp[r] = 1.f / pden[m][r];
#pragma unroll
        for (int n=0;n<4;n++)
#pragma unroll
          for (int r=0;r<4;r++){
            int q = wq0 + m*16 + lh*4 + r;
            int dd = n*16 + l15;
            yb[(size_t)(b_*TT + q)*CC + h*HD + dd] = f2bf(po[m][n][r] * rcp[r]);
          }
    }
}

// ---------------- Output projection (bf16): y [8192,1024] @ wpT^T + bias -> fp32 out
__global__ __launch_bounds__(256, 2)
void proj_gemm(const short* __restrict__ y, const short* __restrict__ wpT,
               const float* __restrict__ bias, float* __restrict__ out)
{
    __shared__ short As[128*64];
    __shared__ short Bs[128*64];
    const int bid = blockIdx.x;
    const int swz = (bid & 7) * 64 + (bid >> 3);   // 512 blocks
    const int bm = swz >> 3, bn = swz & 7;
    const int m0 = bm*128, n0 = bn*128;
    const int t  = threadIdx.x;
    const int wid = t >> 6, lane = t & 63;
    const int wr = wid >> 1, wc = wid & 1;
    const int l15 = lane & 15, lh = lane >> 4;

    f32x4 acc[4][4];
#pragma unroll
    for (int i=0;i<4;i++)
#pragma unroll
      for (int j=0;j<4;j++) acc[i][j] = (f32x4)0.f;

    for (int k0 = 0; k0 < CC; k0 += 64) {
        __syncthreads();
#pragma unroll
        for (int i=0;i<4;i++){
            int u   = (wid*4 + i)*64 + lane;
            int row = u >> 3, c = u & 7;
            int cs  = c ^ (row & 7);
            ASYNC16(&y[(size_t)(m0+row)*CC + k0 + cs*8],   &As[(wid*4+i)*512]);
            ASYNC16(&wpT[(size_t)(n0+row)*CC + k0 + cs*8], &Bs[(wid*4+i)*512]);
        }
        __syncthreads();
#pragma unroll
        for (int ks=0;ks<2;ks++){
            bf16x8 a[4], b[4];
#pragma unroll
            for (int m=0;m<4;m++){
                int row = wr*64 + m*16 + l15;
                a[m] = *reinterpret_cast<const bf16x8*>(&As[row*64 + (((ks<<2)|lh) ^ (row&7))*8]);
            }
#pragma unroll
            for (int n=0;n<4;n++){
                int col = wc*64 + n*16 + l15;
                b[n] = *reinterpret_cast<const bf16x8*>(&Bs[col*64 + (((ks<<2)|lh) ^ (col&7))*8]);
            }
#pragma unroll
            for (int m=0;m<4;m++)
#pragma unroll
              for (int n=0;n<4;n++)
                acc[m][n] = MFMA(a[m], b[n], acc[m][n]);
        }
    }

#pragma unroll
    for (int n=0;n<4;n++){
        int col = n0 + wc*64 + n*16 + l15;
        float bv = bias[col];
#pragma unroll
        for (int m=0;m<4;m++)
#pragma unroll
          for (int r=0;r<4;r++){
            int row = m0 + wr*64 + m*16 + lh*4 + r;
            out[(size_t)row*CC + col] = acc[m][n][r] + bv;
          }
    }
}

extern "C" void kernel_launch(void* const* d_in, const int* in_sizes, int n_in,
                              void* d_out, int out_size, void* d_ws, size_t ws_size,
                              hipStream_t stream) {
    const float* x      = (const float*)d_in[0];
    const float* w_attn = (const float*)d_in[1];
    const float* b_attn = (const float*)d_in[2];
    const float* w_proj = (const float*)d_in[3];
    const float* b_proj = (const float*)d_in[4];
    float* out = (float*)d_out;

    const size_t S = (size_t)BB*TT*CC;   // 8.4M elems
    short* qb  = (short*)d_ws;           // bf16 [B,H,T,HD]
    short* kb  = qb + S;
    short* vtb = kb + S;                 // bf16 [B,H,HD,T]  (V written transposed by qkv)
    short* yx  = vtb + S;                // x-bf16 during prepass+qkv; y-bf16 after attn
    short* wT  = yx + S;                 // bf16 [3072][1024]
    short* wpT = wT + (size_t)NQ*CC;     // bf16 [1024][1024]

    convert_x<<<dim3(S/(256*8)), 256, 0, stream>>>(x, yx);
    transpose_w<<<dim3(CC/64, NQ/64), 256, 0, stream>>>(w_attn, wT, NQ);
    transpose_w<<<dim3(CC/64, CC/64), 256, 0, stream>>>(w_proj, wpT, CC);
    qkv_gemm<<<dim3((BB*TT/128)*(NQ/128)), 256, 0, stream>>>(yx, wT, b_attn, qb, kb, vtb);
    attn_kernel<<<dim3(BB*HH, TT/128), 256, 0, stream>>>(qb, kb, vtb, yx);
    proj_gemm<<<dim3((BB*TT/128)*(CC/128)), 256, 0, stream>>>(yx, wpT, b_proj, out);
}